// Round 6
// baseline (523.677 us; speedup 1.0000x reference)
//
#include <hip/hip_runtime.h>
#include <hip/hip_bf16.h>

#define N_NODES 50000
#define N_EDGES 600000
#define N_GRAPHS 256
#define C 128
#define NB 196            // ceil(N_NODES/256) scan blocks

typedef unsigned short ushort;
typedef unsigned int uint;
typedef __attribute__((ext_vector_type(8))) short bfrag8;
typedef __attribute__((ext_vector_type(4))) float facc4;

// bf16 helpers (bit-level, RNE)
__device__ __forceinline__ ushort f2bf(float v) {
    uint u = __float_as_uint(v);
    u += 0x7FFFu + ((u >> 16) & 1u);
    return (ushort)(u >> 16);
}
__device__ __forceinline__ float bf2f(ushort u) {
    return __uint_as_float(((uint)u) << 16);
}
__device__ __forceinline__ void fsplit(float v, ushort& h, ushort& l) {
    h = f2bf(v);
    l = f2bf(v - bf2f(h));
}

// ---------------------------------------------------------------- degree histogram
__global__ void k_deg(const int* __restrict__ tgt, int* __restrict__ deg) {
    int e = blockIdx.x * blockDim.x + threadIdx.x;
    if (e < N_EDGES) atomicAdd(&deg[tgt[e]], 1);
}

// ---------------------------------------------------------------- scan stage 1: block sums (+ dinv fused)
__global__ __launch_bounds__(256) void k_bsum(const int* __restrict__ deg,
                                              int* __restrict__ bsum,
                                              float* __restrict__ dinv) {
    __shared__ int ws[4];
    int idx = blockIdx.x * 256 + threadIdx.x;
    int v = (idx < N_NODES) ? deg[idx] : 0;
    if (idx < N_NODES) dinv[idx] = 1.0f / fmaxf((float)v, 1.0f);
    int s = v;
#pragma unroll
    for (int off = 1; off < 64; off <<= 1) s += __shfl_xor(s, off);
    if ((threadIdx.x & 63) == 0) ws[threadIdx.x >> 6] = s;
    __syncthreads();
    if (threadIdx.x == 0) bsum[blockIdx.x] = ws[0] + ws[1] + ws[2] + ws[3];
}

// ---------------------------------------------------------------- scan stage 2: scan the 196 block sums
__global__ __launch_bounds__(256) void k_bscan(const int* __restrict__ bsum,
                                               int* __restrict__ boff,
                                               int* __restrict__ rowptr) {
    __shared__ int ws[4];
    int t = threadIdx.x, lane = t & 63, w = t >> 6;
    int v = (t < NB) ? bsum[t] : 0;
    int incl = v;
#pragma unroll
    for (int off = 1; off < 64; off <<= 1) {
        int u = __shfl_up(incl, off);
        if (lane >= off) incl += u;
    }
    if (lane == 63) ws[w] = incl;
    __syncthreads();
    int wo = 0;
    if (w > 0) wo += ws[0];
    if (w > 1) wo += ws[1];
    if (w > 2) wo += ws[2];
    if (t < NB) boff[t] = wo + incl - v;
    if (t == 0) rowptr[N_NODES] = N_EDGES;   // total is known a priori
}

// ---------------------------------------------------------------- scan stage 3: block-local scan + offset
__global__ __launch_bounds__(256) void k_rowptr(const int* __restrict__ deg,
                                                const int* __restrict__ boff,
                                                int* __restrict__ rowptr) {
    __shared__ int ws[4];
    int b = blockIdx.x, t = threadIdx.x;
    int idx = b * 256 + t;
    int lane = t & 63, w = t >> 6;
    int v = (idx < N_NODES) ? deg[idx] : 0;
    int incl = v;
#pragma unroll
    for (int off = 1; off < 64; off <<= 1) {
        int u = __shfl_up(incl, off);
        if (lane >= off) incl += u;
    }
    if (lane == 63) ws[w] = incl;
    __syncthreads();
    int wo = 0;
    if (w > 0) wo += ws[0];
    if (w > 1) wo += ws[1];
    if (w > 2) wo += ws[2];
    if (idx < N_NODES) rowptr[idx] = boff[b] + wo + incl - v;
}

// ---------------------------------------------------------------- CSR fill
__global__ void k_fill(const int* __restrict__ src, const int* __restrict__ tgt,
                       const int* __restrict__ rowptr, int* __restrict__ fill,
                       int* __restrict__ csr_src) {
    int e = blockIdx.x * blockDim.x + threadIdx.x;
    if (e >= N_EDGES) return;
    int d = tgt[e];
    int pos = atomicAdd(&fill[d], 1);
    csr_src[rowptr[d] + pos] = src[e];
}

// ---------------------------------------------------------------- x -> hi/lo planes (cols 128..255)
__global__ __launch_bounds__(256) void k_xsplit(const float* __restrict__ x,
                                                ushort* __restrict__ Ahi,
                                                ushort* __restrict__ Alo) {
    int gid = blockIdx.x * 256 + threadIdx.x;
    if (gid >= N_NODES * 32) return;
    int n = gid >> 5, c4 = (gid & 31) << 2;
    float4 v = *(const float4*)(x + (size_t)n * C + c4);
    ushort4 h, l;
    fsplit(v.x, h.x, l.x); fsplit(v.y, h.y, l.y);
    fsplit(v.z, h.z, l.z); fsplit(v.w, h.w, l.w);
    *(ushort4*)(Ahi + (size_t)n * 256 + 128 + c4) = h;
    *(ushort4*)(Alo + (size_t)n * 256 + 128 + c4) = l;
}

// ---------------------------------------------------------------- weights -> BT planes  BT[l][n][k] = k<128 ? wl[n][k] : wr[n][k-128]
struct WPtrs { const float* wl[4]; const float* wr[4]; };
__global__ __launch_bounds__(256) void k_wsplit(WPtrs wp, ushort* __restrict__ BTh,
                                                ushort* __restrict__ BTl) {
    int gid = blockIdx.x * 256 + threadIdx.x;   // 4*128*256 = 131072
    if (gid >= 4 * 128 * 256) return;
    int l = gid >> 15;
    int rem = gid & 32767;
    int n = rem >> 8, k = rem & 255;
    float v = (k < 128) ? wp.wl[l][n * 128 + k] : wp.wr[l][n * 128 + (k - 128)];
    ushort h, lo;
    fsplit(v, h, lo);
    BTh[gid] = h;
    BTl[gid] = lo;
}

// ---------------------------------------------------------------- gather-mean on planes
// 16 lanes per node, 16B (8-channel) loads per plane -> half the VMEM instrs of r5.
// reads cols 128..255 (h of prev layer, hi+lo), writes cols 0..127 (agg split)
__global__ __launch_bounds__(256) void k_gather(const ushort* __restrict__ Ahi_r,
                                                const ushort* __restrict__ Alo_r,
                                                ushort* __restrict__ Ahi_w,
                                                ushort* __restrict__ Alo_w,
                                                const int* __restrict__ csr_src,
                                                const int* __restrict__ rowptr,
                                                const float* __restrict__ dinv) {
    int node = blockIdx.x * 16 + (threadIdx.x >> 4);
    if (node >= N_NODES) return;
    int c8 = (threadIdx.x & 15) << 3;   // 8-channel segment
    int s = rowptr[node], e = rowptr[node + 1];
    float a[8] = {0.f, 0.f, 0.f, 0.f, 0.f, 0.f, 0.f, 0.f};
    int j = s;
    for (; j + 3 < e; j += 4) {
        int s0 = csr_src[j], s1 = csr_src[j + 1];
        int s2 = csr_src[j + 2], s3 = csr_src[j + 3];
        bfrag8 h0 = *(const bfrag8*)(Ahi_r + (size_t)s0 * 256 + 128 + c8);
        bfrag8 l0 = *(const bfrag8*)(Alo_r + (size_t)s0 * 256 + 128 + c8);
        bfrag8 h1 = *(const bfrag8*)(Ahi_r + (size_t)s1 * 256 + 128 + c8);
        bfrag8 l1 = *(const bfrag8*)(Alo_r + (size_t)s1 * 256 + 128 + c8);
        bfrag8 h2 = *(const bfrag8*)(Ahi_r + (size_t)s2 * 256 + 128 + c8);
        bfrag8 l2 = *(const bfrag8*)(Alo_r + (size_t)s2 * 256 + 128 + c8);
        bfrag8 h3 = *(const bfrag8*)(Ahi_r + (size_t)s3 * 256 + 128 + c8);
        bfrag8 l3 = *(const bfrag8*)(Alo_r + (size_t)s3 * 256 + 128 + c8);
#pragma unroll
        for (int c = 0; c < 8; c++)
            a[c] += (bf2f((ushort)h0[c]) + bf2f((ushort)l0[c]))
                  + (bf2f((ushort)h1[c]) + bf2f((ushort)l1[c]))
                  + (bf2f((ushort)h2[c]) + bf2f((ushort)l2[c]))
                  + (bf2f((ushort)h3[c]) + bf2f((ushort)l3[c]));
    }
    for (; j < e; j++) {
        int s0 = csr_src[j];
        bfrag8 h0 = *(const bfrag8*)(Ahi_r + (size_t)s0 * 256 + 128 + c8);
        bfrag8 l0 = *(const bfrag8*)(Alo_r + (size_t)s0 * 256 + 128 + c8);
#pragma unroll
        for (int c = 0; c < 8; c++)
            a[c] += bf2f((ushort)h0[c]) + bf2f((ushort)l0[c]);
    }
    float sc = dinv[node];
    bfrag8 oh, ol;
#pragma unroll
    for (int c = 0; c < 8; c++) {
        float v = a[c] * sc;
        ushort hh, ll;
        fsplit(v, hh, ll);
        oh[c] = (short)hh;
        ol[c] = (short)ll;
    }
    *(bfrag8*)(Ahi_w + (size_t)node * 256 + c8) = oh;
    *(bfrag8*)(Alo_w + (size_t)node * 256 + c8) = ol;
}

// ---------------------------------------------------------------- split-bf16 MFMA GEMM (v2)
// D = Ahi·Bhi + Ahi·Blo + Alo·Bhi over K=256.
// A staged in LDS in FRAGMENT ORDER: per (plane, mtile) 64 chunks of 16B in exact
// MFMA lane order -> ds_write_b128/ds_read_b128 both lane-stride-16B, zero conflicts.
// B read direct global->reg (128KB weight tile, L2-hot). Register prefetch of next
// K-step's A chunks overlaps the MFMA block.
__global__ __launch_bounds__(256) void k_gemm(const ushort* __restrict__ Ahi,
                                              const ushort* __restrict__ Alo,
                                              const ushort* __restrict__ BTh,
                                              const ushort* __restrict__ BTl,
                                              const float* __restrict__ bl,
                                              ushort* __restrict__ Hhi,
                                              ushort* __restrict__ Hlo) {
    __shared__ __align__(16) short As[2][4096];   // [plane][mtile(8)][chunk(64)][8 shorts]
    const int tid = threadIdx.x;
    const int wave = tid >> 6, lane = tid & 63;
    const int m0 = blockIdx.x * 128;
    const int wm = (wave & 1) * 64;               // wave's M offset
    const int wn = (wave >> 1) * 64;              // wave's N offset
    const int l15 = lane & 15, lk = (lane >> 4) * 8;

    // ---- staging precompute: thread handles 4 of 1024 (plane,mtile,chunk) combos
    const ushort* sp[4];
    short* dp[4];
#pragma unroll
    for (int i = 0; i < 4; i++) {
        int gid = tid + i * 256;
        int p = gid >> 9, rem = gid & 511;
        int mt = rem >> 6, c = rem & 63;
        int row = m0 + mt * 16 + (c & 15);
        if (row >= N_NODES) row = N_NODES - 1;
        sp[i] = (p ? Alo : Ahi) + (size_t)row * 256 + ((c >> 4) << 3);
        dp[i] = &As[p][mt * 512 + c * 8];
    }
    // ---- B fragment pointers (per wave), advanced by k0 each step
    const ushort* pBh[4];
    const ushort* pBl[4];
#pragma unroll
    for (int t = 0; t < 4; t++) {
        int n = wn + t * 16 + l15;
        pBh[t] = BTh + n * 256 + lk;
        pBl[t] = BTl + n * 256 + lk;
    }

    bfrag8 r[4];
#define LOADSTEP(K0) do { \
        r[0] = *(const bfrag8*)(sp[0] + (K0)); \
        r[1] = *(const bfrag8*)(sp[1] + (K0)); \
        r[2] = *(const bfrag8*)(sp[2] + (K0)); \
        r[3] = *(const bfrag8*)(sp[3] + (K0)); \
    } while (0)

    LOADSTEP(0);
    facc4 acc[4][4] = {};
#pragma unroll
    for (int s = 0; s < 8; s++) {
        *(bfrag8*)dp[0] = r[0];
        *(bfrag8*)dp[1] = r[1];
        *(bfrag8*)dp[2] = r[2];
        *(bfrag8*)dp[3] = r[3];
        __syncthreads();
        if (s < 7) LOADSTEP((s + 1) * 32);        // prefetch next K-step's A
        const int k0 = s * 32;
        bfrag8 b[2][4], a[2][4];
#pragma unroll
        for (int t = 0; t < 4; t++) {
            b[0][t] = *(const bfrag8*)(pBh[t] + k0);
            b[1][t] = *(const bfrag8*)(pBl[t] + k0);
        }
#pragma unroll
        for (int t = 0; t < 4; t++) {
            int mt = (wm >> 4) + t;
            a[0][t] = *(const bfrag8*)&As[0][mt * 512 + lane * 8];
            a[1][t] = *(const bfrag8*)&As[1][mt * 512 + lane * 8];
        }
#pragma unroll
        for (int mt = 0; mt < 4; mt++)
#pragma unroll
            for (int nt = 0; nt < 4; nt++) {
                acc[mt][nt] = __builtin_amdgcn_mfma_f32_16x16x32_bf16(a[0][mt], b[0][nt], acc[mt][nt], 0, 0, 0);
                acc[mt][nt] = __builtin_amdgcn_mfma_f32_16x16x32_bf16(a[0][mt], b[1][nt], acc[mt][nt], 0, 0, 0);
                acc[mt][nt] = __builtin_amdgcn_mfma_f32_16x16x32_bf16(a[1][mt], b[0][nt], acc[mt][nt], 0, 0, 0);
            }
        __syncthreads();
    }
#undef LOADSTEP

    // epilogue: bias + relu + split, write cols 128..255
    const int r4 = (lane >> 4) * 4;
#pragma unroll
    for (int mt = 0; mt < 4; mt++) {
#pragma unroll
        for (int nt = 0; nt < 4; nt++) {
            int col = wn + nt * 16 + l15;
            float bias = bl[col];
#pragma unroll
            for (int rr = 0; rr < 4; rr++) {
                int grow = m0 + wm + mt * 16 + r4 + rr;
                if (grow < N_NODES) {
                    float v = fmaxf(acc[mt][nt][rr] + bias, 0.f);
                    ushort h, l;
                    fsplit(v, h, l);
                    Hhi[(size_t)grow * 256 + 128 + col] = h;
                    Hlo[(size_t)grow * 256 + 128 + col] = l;
                }
            }
        }
    }
}

// ---------------------------------------------------------------- graph segment boundaries
__global__ void k_gstart(const int* __restrict__ batch, int* __restrict__ gstart) {
    int g = blockIdx.x * blockDim.x + threadIdx.x;
    if (g > N_GRAPHS) return;
    int lo = 0, hi = N_NODES;
    while (lo < hi) {
        int mid = (lo + hi) >> 1;
        if (batch[mid] < g) lo = mid + 1;
        else hi = mid;
    }
    gstart[g] = lo;
}

// ---------------------------------------------------------------- mean pool per graph (reads planes)
__global__ __launch_bounds__(512) void k_pool(const ushort* __restrict__ Ahi,
                                              const ushort* __restrict__ Alo,
                                              const int* __restrict__ gstart,
                                              float* __restrict__ gmean) {
    __shared__ float part[4][C];
    int g = blockIdx.x;
    int c = threadIdx.x & 127, p = threadIdx.x >> 7;
    int s = gstart[g], e = gstart[g + 1];
    float sum = 0.f;
    for (int n = s + p; n < e; n += 4) {
        size_t o = (size_t)n * 256 + 128 + c;
        sum += bf2f(Ahi[o]) + bf2f(Alo[o]);
    }
    part[p][c] = sum;
    __syncthreads();
    if (p == 0) {
        float tot = part[0][c] + part[1][c] + part[2][c] + part[3][c];
        float cnt = fmaxf((float)(e - s), 1.0f);
        gmean[g * C + c] = tot / cnt;
    }
}

// ---------------------------------------------------------------- classifier head
__global__ __launch_bounds__(256) void k_final(const ushort* __restrict__ Ahi,
                                               const ushort* __restrict__ Alo,
                                               const float* __restrict__ gmean,
                                               const int* __restrict__ root,
                                               const float* __restrict__ wcls,
                                               const float* __restrict__ bcls,
                                               float* __restrict__ out) {
    __shared__ float red[8];
    int g = blockIdx.x, t = threadIdx.x;
    float v;
    if (t < 128) {
        size_t o = (size_t)root[g] * 256 + 128 + t;
        v = bf2f(Ahi[o]) + bf2f(Alo[o]);
    } else {
        v = gmean[g * C + (t - 128)];
    }
    float p0 = v * wcls[t];
    float p1 = v * wcls[256 + t];
#pragma unroll
    for (int off = 32; off; off >>= 1) {
        p0 += __shfl_down(p0, off);
        p1 += __shfl_down(p1, off);
    }
    int wid = t >> 6;
    if ((t & 63) == 0) { red[wid] = p0; red[4 + wid] = p1; }
    __syncthreads();
    if (t == 0) {
        out[g * 2 + 0] = red[0] + red[1] + red[2] + red[3] + bcls[0];
        out[g * 2 + 1] = red[4] + red[5] + red[6] + red[7] + bcls[1];
    }
}

// ---------------------------------------------------------------- launch
extern "C" void kernel_launch(void* const* d_in, const int* in_sizes, int n_in,
                              void* d_out, int out_size, void* d_ws, size_t ws_size,
                              hipStream_t stream) {
    const float* x = (const float*)d_in[0];
    const int* ei = (const int*)d_in[1];
    const int* src = ei;
    const int* tgt = ei + N_EDGES;
    const int* root = (const int*)d_in[2];
    const int* batch = (const int*)d_in[3];
    WPtrs wp;
    wp.wl[0] = (const float*)d_in[4];  wp.wr[0] = (const float*)d_in[6];
    wp.wl[1] = (const float*)d_in[7];  wp.wr[1] = (const float*)d_in[9];
    wp.wl[2] = (const float*)d_in[10]; wp.wr[2] = (const float*)d_in[12];
    wp.wl[3] = (const float*)d_in[13]; wp.wr[3] = (const float*)d_in[15];
    const float* blv[4] = {(const float*)d_in[5], (const float*)d_in[8],
                           (const float*)d_in[11], (const float*)d_in[14]};
    const float* wcls = (const float*)d_in[16];
    const float* bcls = (const float*)d_in[17];
    float* out = (float*)d_out;

    // workspace carve-up
    ushort* Ahi = (ushort*)d_ws;                      // 50000*256 bf16
    ushort* Alo = Ahi + (size_t)N_NODES * 256;        // 50000*256
    ushort* BTh = Alo + (size_t)N_NODES * 256;        // 4*128*256
    ushort* BTl = BTh + 4 * 128 * 256;                // 4*128*256
    int* deg = (int*)(BTl + 4 * 128 * 256);           // 50000
    float* dinv = (float*)(deg + N_NODES);            // 50000
    int* rowptr = (int*)(dinv + N_NODES);             // 50001
    int* fill = rowptr + N_NODES + 1;                 // 50000
    int* csr_src = fill + N_NODES;                    // 600000
    int* bsum = csr_src + N_EDGES;                    // 196
    int* boff = bsum + 256;                           // 196
    int* gstart = boff + 256;                         // 257
    float* gmean = (float*)(gstart + 260);            // 256*128

    hipMemsetAsync(deg, 0, N_NODES * sizeof(int), stream);
    hipMemsetAsync(fill, 0, N_NODES * sizeof(int), stream);
    k_deg<<<(N_EDGES + 255) / 256, 256, 0, stream>>>(tgt, deg);
    k_bsum<<<NB, 256, 0, stream>>>(deg, bsum, dinv);
    k_bscan<<<1, 256, 0, stream>>>(bsum, boff, rowptr);
    k_rowptr<<<NB, 256, 0, stream>>>(deg, boff, rowptr);
    k_fill<<<(N_EDGES + 255) / 256, 256, 0, stream>>>(src, tgt, rowptr, fill, csr_src);
    k_gstart<<<1, 512, 0, stream>>>(batch, gstart);
    k_xsplit<<<(N_NODES * 32 + 255) / 256, 256, 0, stream>>>(x, Ahi, Alo);
    k_wsplit<<<(4 * 128 * 256 + 255) / 256, 256, 0, stream>>>(wp, BTh, BTl);

    for (int l = 0; l < 4; l++) {
        k_gather<<<(N_NODES + 15) / 16, 256, 0, stream>>>(Ahi, Alo, Ahi, Alo,
                                                          csr_src, rowptr, dinv);
        k_gemm<<<(N_NODES + 127) / 128, 256, 0, stream>>>(
            Ahi, Alo, BTh + l * 32768, BTl + l * 32768, blv[l], Ahi, Alo);
    }
    k_pool<<<N_GRAPHS, 512, 0, stream>>>(Ahi, Alo, gstart, gmean);
    k_final<<<N_GRAPHS, 256, 0, stream>>>(Ahi, Alo, gmean, root, wcls, bcls, out);
}